// Round 8
// baseline (288.127 us; speedup 1.0000x reference)
//
#include <hip/hip_runtime.h>
#include <hip/hip_bf16.h>

#define B_ 2
#define C_ 512
#define HW_ 4096
#define K_ 512
#define EPS_ 1e-6f
#define SCALE_ 0.04419417382415922f   // 512^-0.5
#define NEG_INF_ (-1e30f)

typedef __attribute__((ext_vector_type(8))) __bf16 bf16x8;
typedef __attribute__((ext_vector_type(4))) float f32x4;
typedef __attribute__((ext_vector_type(16))) float f32x16;

__device__ __forceinline__ unsigned short f2bf(float f) {
  union { float f; unsigned u; } v; v.f = f;
  unsigned r = v.u + 0x7fffu + ((v.u >> 16) & 1u);
  return (unsigned short)(r >> 16);
}
__device__ __forceinline__ float bf2f(unsigned short h) {
  union { unsigned u; float f; } v; v.u = ((unsigned)h) << 16;
  return v.f;
}

// direct global->LDS DMA, 16B per lane. LDS dst = wave-uniform base + lane*16.
__device__ __forceinline__ void gld_lds16(const unsigned short* g, unsigned short* l) {
  __builtin_amdgcn_global_load_lds((const __attribute__((address_space(1))) void*)g,
                                   (__attribute__((address_space(3))) void*)l, 16, 0, 0);
}

// pipelined barrier: wait only for all but the newest 4 DMA loads (the depth-2
// prefetch stays in flight across the barrier), then barrier. Raw asm so the
// compiler's vmcnt(0)-before-s_barrier convention is bypassed.
#define PIPE_BAR() asm volatile("s_waitcnt vmcnt(4)\n\ts_barrier" ::: "memory")
// softmax barrier: LDS-only ordering; leaves global->LDS DMA in flight.
#define SOFT_BAR() asm volatile("s_waitcnt lgkmcnt(0)\n\ts_barrier" ::: "memory")

// ---------------- GroupNorm sums: 1024 blocks, one per (b,g,row); atomic partials ----------------
__global__ void gn_sums(const float* __restrict__ x, float* __restrict__ stats) {
  int bid = blockIdx.x;
  int bg = bid >> 4, row = bid & 15;
  int b = bg >> 5, g = bg & 31;
  const float* base = x + ((size_t)(b * C_ + g * 16 + row)) * HW_;
  float s = 0.f, s2 = 0.f;
  int t = threadIdx.x;
  #pragma unroll
  for (int i = 0; i < 4; ++i) {
    float4 v = *reinterpret_cast<const float4*>(base + (size_t)(t + i * 256) * 4);
    s  += v.x + v.y + v.z + v.w;
    s2 += v.x * v.x + v.y * v.y + v.z * v.z + v.w * v.w;
  }
  for (int off = 32; off; off >>= 1) { s += __shfl_down(s, off); s2 += __shfl_down(s2, off); }
  __shared__ float rs[4], rs2[4];
  int w = t >> 6;
  if ((t & 63) == 0) { rs[w] = s; rs2[w] = s2; }
  __syncthreads();
  if (t == 0) {
    atomicAdd(&stats[bg], rs[0] + rs[1] + rs[2] + rs[3]);
    atomicAdd(&stats[64 + bg], rs2[0] + rs2[1] + rs2[2] + rs2[3]);
  }
}

// ------------- normalize + transpose: x(b,c,n) f32 -> t(b,n,c) bf16 -------------
__global__ void build_t(const float* __restrict__ x, const float* __restrict__ stats,
                        const float* __restrict__ gamma, const float* __restrict__ beta,
                        unsigned short* __restrict__ tb) {
  __shared__ float lds[64 * 69];
  int n0 = blockIdx.x * 64, c0 = blockIdx.y * 64, b = blockIdx.z;
  int t = threadIdx.x;
  {
    int cl = t >> 2, ch = t & 3;
    int c = c0 + cl;
    int bg = b * 32 + (c >> 4);
    float s = stats[bg], s2v = stats[64 + bg];
    float mean = s * (1.f / 65536.f);
    float var = s2v * (1.f / 65536.f) - mean * mean;
    float rstd = rsqrtf(var + EPS_);
    float ga = gamma[c] * rstd;
    float be = beta[c] - mean * ga;
    const float* xr = x + ((size_t)(b * C_ + c)) * HW_ + n0 + ch * 16;
    #pragma unroll
    for (int i = 0; i < 4; ++i) {
      float4 v = *reinterpret_cast<const float4*>(xr + i * 4);
      int nl = ch * 16 + i * 4;
      lds[cl * 69 + nl + 0] = v.x * ga + be;
      lds[cl * 69 + nl + 1] = v.y * ga + be;
      lds[cl * 69 + nl + 2] = v.z * ga + be;
      lds[cl * 69 + nl + 3] = v.w * ga + be;
    }
  }
  __syncthreads();
  {
    int nl = t >> 2, cw = t & 3;
    unsigned short* orow = tb + ((size_t)(b * HW_ + n0 + nl)) * C_ + c0 + cw * 16;
    #pragma unroll
    for (int i = 0; i < 4; ++i) {
      ushort4 o4;
      o4.x = f2bf(lds[(cw * 16 + i * 4 + 0) * 69 + nl]);
      o4.y = f2bf(lds[(cw * 16 + i * 4 + 1) * 69 + nl]);
      o4.z = f2bf(lds[(cw * 16 + i * 4 + 2) * 69 + nl]);
      o4.w = f2bf(lds[(cw * 16 + i * 4 + 3) * 69 + nl]);
      *reinterpret_cast<ushort4*>(orow + i * 4) = o4;
    }
  }
}

// ---------------- f32 -> bf16 weight cast, all 4 weights in one launch ----------------
__global__ void cast_w4(const float* __restrict__ s0, const float* __restrict__ s1,
                        const float* __restrict__ s2, const float* __restrict__ s3,
                        unsigned short* __restrict__ dst) {
  int which = blockIdx.y;
  const float* src = which == 0 ? s0 : which == 1 ? s1 : which == 2 ? s2 : s3;
  int i = (blockIdx.x * 256 + threadIdx.x) * 4;
  float4 v = *reinterpret_cast<const float4*>(src + i);
  ushort4 o; o.x = f2bf(v.x); o.y = f2bf(v.y); o.z = f2bf(v.z); o.w = f2bf(v.w);
  *reinterpret_cast<ushort4*>(dst + (size_t)which * 262144 + i) = o;
}

// ---------------- fused Q/K/V^T projections, one launch ----------------
// z = which*2 + b; which 0: q = t.wq^T (bias/col), 1: k (bias/col), 2: vT = wv.t^T (bias/row)
__global__ __launch_bounds__(256, 2) void gemm_qkv(
    const unsigned short* __restrict__ tb, const unsigned short* __restrict__ wqkv,
    const float* __restrict__ bq, const float* __restrict__ bk, const float* __restrict__ bv,
    unsigned short* __restrict__ qb, unsigned short* __restrict__ kb,
    unsigned short* __restrict__ vTb) {
  __shared__ unsigned short Al[2][128 * 64];
  __shared__ unsigned short Bl[2][128 * 64];
  int z = blockIdx.z;
  int which = z >> 1, b = z & 1;
  const unsigned short* Ab = (which < 2) ? (tb + (size_t)b * HW_ * K_) : (wqkv + 2 * 262144);
  const unsigned short* Bb = (which < 2) ? (wqkv + which * 262144) : (tb + (size_t)b * HW_ * K_);
  int m0 = (which < 2) ? blockIdx.y * 128 : blockIdx.x * 128;
  int n0 = (which < 2) ? blockIdx.x * 128 : blockIdx.y * 128;
  int N = (which < 2) ? 512 : HW_;
  unsigned short* Cb = (which == 0) ? (qb + (size_t)b * HW_ * K_)
                     : (which == 1) ? (kb + (size_t)b * HW_ * K_)
                                    : (vTb + (size_t)b * C_ * HW_);
  const float* bias = (which == 0) ? bq : (which == 1) ? bk : bv;
  int t = threadIdx.x, lane = t & 63, w = t >> 6;
  int l15 = lane & 15, quad = lane >> 4;
  int mw = (w & 1) * 64, nw = (w >> 1) * 64;
  int sr8 = lane >> 3, sb = lane & 7;
  f32x4 acc[4][4] = {};

  #define G_STAGE(KC) do {                                                          \
    int pb = (KC) & 1;                                                              \
    _Pragma("unroll")                                                               \
    for (int q = 0; q < 4; ++q) {                                                   \
      int row = w * 32 + q * 8 + sr8;                                               \
      int gb = sb ^ (row & 7);                                                      \
      gld_lds16(Ab + (size_t)(m0 + row) * K_ + (KC) * 64 + gb * 8, &Al[pb][(w * 32 + q * 8) * 64]); \
      gld_lds16(Bb + (size_t)(n0 + row) * K_ + (KC) * 64 + gb * 8, &Bl[pb][(w * 32 + q * 8) * 64]); \
    }                                                                               \
  } while (0)

  G_STAGE(0);
  __syncthreads();
  for (int kc = 0; kc < 8; ++kc) {
    if (kc < 7) G_STAGE(kc + 1);
    const unsigned short* Ac = Al[kc & 1];
    const unsigned short* Bc = Bl[kc & 1];
    #pragma unroll
    for (int kk = 0; kk < 2; ++kk) {
      bf16x8 af[4];
      #pragma unroll
      for (int mt = 0; mt < 4; ++mt)
        af[mt] = *reinterpret_cast<const bf16x8*>(
            &Ac[(mw + mt * 16 + l15) * 64 + (((kk * 4 + quad) ^ (l15 & 7)) << 3)]);
      #pragma unroll
      for (int nt = 0; nt < 4; ++nt) {
        bf16x8 bfr = *reinterpret_cast<const bf16x8*>(
            &Bc[(nw + nt * 16 + l15) * 64 + (((kk * 4 + quad) ^ (l15 & 7)) << 3)]);
        #pragma unroll
        for (int mt = 0; mt < 4; ++mt)
          acc[mt][nt] = __builtin_amdgcn_mfma_f32_16x16x32_bf16(af[mt], bfr, acc[mt][nt], 0, 0, 0);
      }
    }
    __syncthreads();
  }
  #undef G_STAGE
  #pragma unroll
  for (int mt = 0; mt < 4; ++mt)
    #pragma unroll
    for (int nt = 0; nt < 4; ++nt)
      #pragma unroll
      for (int rr = 0; rr < 4; ++rr) {
        int row = m0 + mw + mt * 16 + quad * 4 + rr;
        int col = n0 + nw + nt * 16 + l15;
        float v = acc[mt][nt][rr] + ((which < 2) ? bias[col] : bias[row]);
        Cb[(size_t)row * N + col] = f2bf(v);
      }
}

// ---------------- final projection + residual (f32 out) ----------------
template <int MODE>
__global__ __launch_bounds__(256, 2) void gemm_bt(
    const unsigned short* __restrict__ A, long sA,
    const unsigned short* __restrict__ B, long sB,
    void* __restrict__ Cv, long sC, int M, int N,
    const float* __restrict__ bias,
    const float* __restrict__ resid, long sR) {
  __shared__ unsigned short Al[2][128 * 64];
  __shared__ unsigned short Bl[2][128 * 64];
  int z = blockIdx.z;
  const unsigned short* Ab = A + (size_t)z * sA;
  const unsigned short* Bb = B + (size_t)z * sB;
  int n0 = blockIdx.x * 128, m0 = blockIdx.y * 128;
  int t = threadIdx.x, lane = t & 63, w = t >> 6;
  int l15 = lane & 15, quad = lane >> 4;
  int mw = (w & 1) * 64, nw = (w >> 1) * 64;
  int sr8 = lane >> 3, sb = lane & 7;
  f32x4 acc[4][4] = {};

  #define G_STAGE(KC) do {                                                          \
    int pb = (KC) & 1;                                                              \
    _Pragma("unroll")                                                               \
    for (int q = 0; q < 4; ++q) {                                                   \
      int row = w * 32 + q * 8 + sr8;                                               \
      int gb = sb ^ (row & 7);                                                      \
      gld_lds16(Ab + (size_t)(m0 + row) * K_ + (KC) * 64 + gb * 8, &Al[pb][(w * 32 + q * 8) * 64]); \
      gld_lds16(Bb + (size_t)(n0 + row) * K_ + (KC) * 64 + gb * 8, &Bl[pb][(w * 32 + q * 8) * 64]); \
    }                                                                               \
  } while (0)

  G_STAGE(0);
  __syncthreads();
  for (int kc = 0; kc < 8; ++kc) {
    if (kc < 7) G_STAGE(kc + 1);
    const unsigned short* Ac = Al[kc & 1];
    const unsigned short* Bc = Bl[kc & 1];
    #pragma unroll
    for (int kk = 0; kk < 2; ++kk) {
      bf16x8 af[4];
      #pragma unroll
      for (int mt = 0; mt < 4; ++mt)
        af[mt] = *reinterpret_cast<const bf16x8*>(
            &Ac[(mw + mt * 16 + l15) * 64 + (((kk * 4 + quad) ^ (l15 & 7)) << 3)]);
      #pragma unroll
      for (int nt = 0; nt < 4; ++nt) {
        bf16x8 bfr = *reinterpret_cast<const bf16x8*>(
            &Bc[(nw + nt * 16 + l15) * 64 + (((kk * 4 + quad) ^ (l15 & 7)) << 3)]);
        #pragma unroll
        for (int mt = 0; mt < 4; ++mt)
          acc[mt][nt] = __builtin_amdgcn_mfma_f32_16x16x32_bf16(af[mt], bfr, acc[mt][nt], 0, 0, 0);
      }
    }
    __syncthreads();
  }
  #undef G_STAGE
  #pragma unroll
  for (int mt = 0; mt < 4; ++mt)
    #pragma unroll
    for (int nt = 0; nt < 4; ++nt)
      #pragma unroll
      for (int rr = 0; rr < 4; ++rr) {
        int row = m0 + mw + mt * 16 + quad * 4 + rr;
        int col = n0 + nw + nt * 16 + l15;
        float v = acc[mt][nt][rr];
        if (MODE == 0) {
          v += bias[col];
          reinterpret_cast<unsigned short*>(Cv)[(size_t)z * sC + (size_t)row * N + col] = f2bf(v);
        } else if (MODE == 1) {
          v += bias[row];
          reinterpret_cast<unsigned short*>(Cv)[(size_t)z * sC + (size_t)row * N + col] = f2bf(v);
        } else {
          v += bias[row];
          v += resid[(size_t)z * sR + (size_t)row * N + col];
          reinterpret_cast<float*>(Cv)[(size_t)z * sC + (size_t)row * N + col] = v;
        }
      }
}

// ------- flash attention: Br=64, Bc=256; 3-buffer depth-2 DMA pipeline, raw barriers -------
// 1 block/CU (register-pinned). Chunk barriers wait vmcnt(4) only: the depth-2 prefetch
// (issued one region earlier) stays in flight across the barrier, so staging latency is
// double-shadowed. Softmax barriers drain lgkm only. Explicit vmcnt(0) before exit.
__global__ __launch_bounds__(512, 2) void attn(
    const unsigned short* __restrict__ qg, const unsigned short* __restrict__ kg,
    const unsigned short* __restrict__ vg,  // vT: (b, c, n)
    unsigned short* __restrict__ opart, float* __restrict__ mpart, float* __restrict__ lpart) {
  __shared__ unsigned short KVb[3 * 16384];   // 3 x 32KB chunk buffers (128 rows x 128 cols)
  __shared__ unsigned short Pl[64 * 264];     // 33792 B
  __shared__ float sm_m[64], sm_l[64], sm_alpha[64], sm_red[128];
  int qt = blockIdx.x, jh = blockIdx.y, b = blockIdx.z;
  int t = threadIdx.x, lane = t & 63, w = t >> 6;
  int l15 = lane & 15, quad = lane >> 4;
  int l31 = lane & 31, hl = lane >> 5;
  int rw = w & 3, cw = w >> 2;      // S phase: 4 row-groups(16) x 2 col-halves
  int rw2 = w & 1, dg = w >> 1;     // PV phase: 2 row-groups(32) x 4 d-slots
  int m0 = qt * 64;
  if (t < 64) { sm_m[t] = NEG_INF_; sm_l[t] = 0.f; }

  // staging geometry: thread stages 4 x 16B; wave w covers 1KB blocks w*4+q (4 rows each)
  int st_r[4], st_kb[4];
  #pragma unroll
  for (int q = 0; q < 4; ++q) {
    int blk = w * 4 + q;
    st_r[q] = blk * 4 + (lane >> 4);          // row 0..127 within chunk
    st_kb[q] = (lane & 15) ^ (st_r[q] & 7);   // logical 16B block (col/8), phys slot lane&15
  }

  #define STAGE_K(JC, KC, J0, WB) do {                                               \
    const unsigned short* gbp = kg + ((size_t)(b * HW_ + (J0) + (JC) * 128)) * K_ + (KC) * 128; \
    unsigned short* lbp = KVb + (WB) * 16384;                                        \
    _Pragma("unroll")                                                                \
    for (int q = 0; q < 4; ++q)                                                      \
      gld_lds16(gbp + (size_t)st_r[q] * K_ + st_kb[q] * 8, lbp + (w * 4 + q) * 512); \
  } while (0)

  #define STAGE_V(DC, JC, J0, WB) do {                                               \
    const unsigned short* gbp = vg + ((size_t)(b * K_ + (DC) * 128)) * HW_ + (J0) + (JC) * 128; \
    unsigned short* lbp = KVb + (WB) * 16384;                                        \
    _Pragma("unroll")                                                                \
    for (int q = 0; q < 4; ++q)                                                      \
      gld_lds16(gbp + (size_t)st_r[q] * HW_ + st_kb[q] * 8, lbp + (w * 4 + q) * 512); \
  } while (0)

  bf16x8 qa[16];
  {
    const unsigned short* qrow = qg + ((size_t)(b * HW_ + m0 + rw * 16 + l15)) * K_ + quad * 8;
    #pragma unroll
    for (int kk = 0; kk < 16; ++kk)
      qa[kk] = *reinterpret_cast<const bf16x8*>(qrow + kk * 32);
  }
  f32x16 acc_o[4] = {};    // [dc]: d = dc*128 + dg*32 + l31

  int j0 = jh * 2048;
  STAGE_K(0, 0, j0, 0);
  STAGE_K(0, 1, j0, 1);
  __syncthreads();         // full drain: chunks 0,1 resident; sm init published
  int bs = 0;              // buffer of this iter's chunk 0; advances by 16%3=1 per iter

  for (int it = 0; it < 8; ++it, j0 += 256) {
    int j0n = (it < 7) ? (j0 + 256) : jh * 2048;   // next-iter K base (dummy refetch on last)
    f32x4 acc_s[8] = {};
    // ===== S: 8 chunks (global idx g=c), read buf (bs+g)%3, stage g+2 =====
    #pragma unroll
    for (int c = 0; c < 8; ++c) {
      int rb = bs + (c % 3);       if (rb >= 3) rb -= 3;
      int wb = bs + ((c + 2) % 3); if (wb >= 3) wb -= 3;
      if (c < 6)      { STAGE_K((c + 2) >> 2, (c + 2) & 3, j0, wb); }
      else if (c == 6){ STAGE_V(0, 0, j0, wb); }   // PV chunk 0 (g=8)
      else            { STAGE_V(1, 0, j0, wb); }   // PV chunk 1 (g=9): dc=1, jc=0
      const unsigned short* bufc = KVb + rb * 16384;
      int jc = c >> 2, kc = c & 3;
      #pragma unroll
      for (int kk = 0; kk < 4; ++kk)
        #pragma unroll
        for (int ct = 0; ct < 4; ++ct) {
          int jr = cw * 64 + ct * 16 + l15;
          bf16x8 bfr = *reinterpret_cast<const bf16x8*>(
              &bufc[jr * 128 + (((kk * 4 + quad) ^ (l15 & 7)) << 3)]);
          acc_s[jc * 4 + ct] = __builtin_amdgcn_mfma_f32_16x16x32_bf16(qa[kc * 4 + kk], bfr, acc_s[jc * 4 + ct], 0, 0, 0);
        }
      PIPE_BAR();
    }
    // ===== softmax (LDS-only barriers; V prefetch rides through) =====
    float mx[4];
    #pragma unroll
    for (int rr = 0; rr < 4; ++rr) {
      float m = NEG_INF_;
      #pragma unroll
      for (int s = 0; s < 8; ++s) {
        acc_s[s][rr] *= SCALE_;
        m = fmaxf(m, acc_s[s][rr]);
      }
      mx[rr] = m;
    }
    #pragma unroll
    for (int off = 1; off < 16; off <<= 1)
      #pragma unroll
      for (int rr = 0; rr < 4; ++rr)
        mx[rr] = fmaxf(mx[rr], __shfl_xor(mx[rr], off));
    if (l15 == 0)
      #pragma unroll
      for (int rr = 0; rr < 4; ++rr)
        sm_red[cw * 64 + rw * 16 + quad * 4 + rr] = mx[rr];
    SOFT_BAR();
    if (t < 64) {
      float mnew = fmaxf(sm_m[t], fmaxf(sm_red[t], sm_red[64 + t]));
      sm_alpha[t] = __expf(sm_m[t] - mnew);
      sm_m[t] = mnew;
    }
    SOFT_BAR();
    float sum[4] = {0.f, 0.f, 0.f, 0.f};
    #pragma unroll
    for (int s = 0; s < 8; ++s)
      #pragma unroll
      for (int rr = 0; rr < 4; ++rr) {
        int rowl = rw * 16 + quad * 4 + rr;
        float p = __expf(acc_s[s][rr] - sm_m[rowl]);
        sum[rr] += p;
        Pl[rowl * 264 + (s >> 2) * 128 + cw * 64 + (s & 3) * 16 + l15] = f2bf(p);
      }
    #pragma unroll
    for (int off = 1; off < 16; off <<= 1)
      #pragma unroll
      for (int rr = 0; rr < 4; ++rr)
        sum[rr] += __shfl_xor(sum[rr], off);
    if (l15 == 0)
      #pragma unroll
      for (int rr = 0; rr < 4; ++rr)
        sm_red[cw * 64 + rw * 16 + quad * 4 + rr] = sum[rr];
    // rescale O by alpha (32x32 C/D row mapping); sm_alpha valid since SOFT_BAR #2
    #pragma unroll
    for (int r16 = 0; r16 < 16; ++r16) {
      int row = rw2 * 32 + (r16 & 3) + 8 * (r16 >> 2) + 4 * hl;
      float a = sm_alpha[row];
      #pragma unroll
      for (int dc = 0; dc < 4; ++dc)
        acc_o[dc][r16] *= a;
    }
    SOFT_BAR();              // Pl + sum partials published
    if (t < 64)
      sm_l[t] = sm_l[t] * sm_alpha[t] + sm_red[t] + sm_red[64 + t];
    // ===== PV: 8 chunks (g=8+c, dc-inner: jc=c>>2, dc=c&3); pa_r reused across dc =====
    bf16x8 pa_r[8];
    #pragma unroll
    for (int c = 0; c < 8; ++c) {
      int g = 8 + c;
      int rb = bs + (g % 3);       if (rb >= 3) rb -= 3;
      int wb = bs + ((g + 2) % 3); if (wb >= 3) wb -= 3;
      int jc = c >> 2, dc = c & 3;
      if ((c & 3) == 0) {
        #pragma unroll
        for (int ksx = 0; ksx < 8; ++ksx)
          pa_r[ksx] = *reinterpret_cast<const bf16x8*>(
              &Pl[(rw2 * 32 + l31) * 264 + jc * 128 + ksx * 16 + hl * 8]);
      }
      if (c < 6)      { STAGE_V((c + 2) & 3, (c + 2) >> 2, j0, wb); }
      else if (c == 6){ STAGE_K(0, 0, j0n, wb); }   // next iter g=16
      else            { STAGE_K(0, 1, j0n, wb); }   // next iter g=17
      const unsigned short* bufc = KVb + rb * 16384;
      #pragma unroll
      for (int ksx = 0; ksx < 8; ++ksx) {
        bf16x8 vb = *reinterpret_cast<const bf16x8*>(
            &bufc[(dg * 32 + l31) * 128 + (((ksx * 2 + hl) ^ (l31 & 7)) << 3)]);
        acc_o[dc] = __builtin_amdgcn_mfma_f32_32x32x16_bf16(pa_r[ksx], vb, acc_o[dc], 0, 0, 0);
      }
      PIPE_BAR();
    }
    bs += 1; if (bs >= 3) bs = 0;
  }
  #undef STAGE_K
  #undef STAGE_V
  // drain dummy prefetches before LDS deallocation / stores
  asm volatile("s_waitcnt vmcnt(0)" ::: "memory");
  // write partials (unnormalized O in bf16, running m and l)
  int part = jh * 2 + b;
  unsigned short* ob = opart + ((size_t)part * HW_ + m0) * 512;
  #pragma unroll
  for (int dc = 0; dc < 4; ++dc) {
    int d = dc * 128 + dg * 32 + l31;
    #pragma unroll
    for (int r16 = 0; r16 < 16; ++r16) {
      int row = rw2 * 32 + (r16 & 3) + 8 * (r16 >> 2) + 4 * hl;
      ob[(size_t)row * 512 + d] = f2bf(acc_o[dc][r16]);
    }
  }
  if (t < 64) {
    mpart[(size_t)part * HW_ + m0 + t] = sm_m[t];
    lpart[(size_t)part * HW_ + m0 + t] = sm_l[t];
  }
}

// ---------------- merge the two j-split halves ----------------
__global__ void merge_o(const unsigned short* __restrict__ opart, const float* __restrict__ mpart,
                        const float* __restrict__ lpart, unsigned short* __restrict__ om) {
  int rg = blockIdx.x;            // b*4096 + n
  int b = rg >> 12, n = rg & 4095;
  float m[2], l[2], M = NEG_INF_;
  #pragma unroll
  for (int p = 0; p < 2; ++p) {
    size_t r = (size_t)(p * 2 + b) * HW_ + n;
    m[p] = mpart[r]; l[p] = lpart[r];
    M = fmaxf(M, m[p]);
  }
  float wgt[2], L = 0.f;
  #pragma unroll
  for (int p = 0; p < 2; ++p) { wgt[p] = __expf(m[p] - M); L += l[p] * wgt[p]; }
  float inv = 1.f / L;
  unsigned short* orow = om + (size_t)rg * 512;
  for (int d = threadIdx.x; d < 512; d += 256) {
    float acc = 0.f;
    #pragma unroll
    for (int p = 0; p < 2; ++p)
      acc += bf2f(opart[((size_t)(p * 2 + b) * HW_ + n) * 512 + d]) * wgt[p];
    orow[d] = f2bf(acc * inv);
  }
}

extern "C" void kernel_launch(void* const* d_in, const int* in_sizes, int n_in,
                              void* d_out, int out_size, void* d_ws, size_t ws_size,
                              hipStream_t stream) {
  const float* x     = (const float*)d_in[0];
  const float* gamma = (const float*)d_in[1];
  const float* beta  = (const float*)d_in[2];
  const float* wq    = (const float*)d_in[3];
  const float* bq    = (const float*)d_in[4];
  const float* wk    = (const float*)d_in[5];
  const float* bk    = (const float*)d_in[6];
  const float* wv    = (const float*)d_in[7];
  const float* bv    = (const float*)d_in[8];
  const float* wp    = (const float*)d_in[9];
  const float* bp    = (const float*)d_in[10];
  float* out = (float*)d_out;

  char* ws = (char*)d_ws;
  size_t o = 0;
  float* stats          = (float*)(ws + o);          o += 1024;
  unsigned short* tb    = (unsigned short*)(ws + o); o += 8388608;   // om aliases tb after attn
  unsigned short* qb    = (unsigned short*)(ws + o); o += 8388608;
  unsigned short* kb    = (unsigned short*)(ws + o); o += 8388608;
  unsigned short* vTb   = (unsigned short*)(ws + o); o += 8388608;
  unsigned short* wqb   = (unsigned short*)(ws + o); o += 524288;
  unsigned short* wkb   = (unsigned short*)(ws + o); o += 524288;
  unsigned short* wvb   = (unsigned short*)(ws + o); o += 524288;
  unsigned short* wpb   = (unsigned short*)(ws + o); o += 524288;
  unsigned short* opart = (unsigned short*)(ws + o); o += 16777216;  // 4 parts bf16
  float* mpart          = (float*)(ws + o);          o += 65536;
  float* lpart          = (float*)(ws + o);          o += 65536;
  unsigned short* om    = tb;                                        // alias

  hipMemsetAsync(stats, 0, 512, stream);
  gn_sums<<<1024, 256, 0, stream>>>(x, stats);
  build_t<<<dim3(64, 8, 2), 256, 0, stream>>>(x, stats, gamma, beta, tb);
  cast_w4<<<dim3(256, 4), 256, 0, stream>>>(wq, wk, wv, wp, wqb);
  // fused q,k,vT projections
  gemm_qkv<<<dim3(4, 32, 6), 256, 0, stream>>>(tb, wqb, bq, bk, bv, qb, kb, vTb);
  attn<<<dim3(64, 2, 2), 512, 0, stream>>>(qb, kb, vTb, opart, mpart, lpart);
  merge_o<<<8192, 256, 0, stream>>>(opart, mpart, lpart, om);
  // out[c][n] = x + wp[c][:] . o[n][:] + bp[c]
  gemm_bt<2><<<dim3(32, 4, 2), 256, 0, stream>>>(wpb, 0, om, (long)HW_ * K_, out, (long)C_ * HW_, C_, HW_, bp, x, (long)C_ * HW_);
}

// Round 9
// 277.252 us; speedup vs baseline: 1.0392x; 1.0392x over previous
//
#include <hip/hip_runtime.h>
#include <hip/hip_bf16.h>

#define B_ 2
#define C_ 512
#define HW_ 4096
#define K_ 512
#define EPS_ 1e-6f
#define SCALE_ 0.04419417382415922f   // 512^-0.5
#define NEG_INF_ (-1e30f)

typedef __attribute__((ext_vector_type(8))) __bf16 bf16x8;
typedef __attribute__((ext_vector_type(4))) float f32x4;
typedef __attribute__((ext_vector_type(16))) float f32x16;

__device__ __forceinline__ unsigned short f2bf(float f) {
  union { float f; unsigned u; } v; v.f = f;
  unsigned r = v.u + 0x7fffu + ((v.u >> 16) & 1u);
  return (unsigned short)(r >> 16);
}
__device__ __forceinline__ float bf2f(unsigned short h) {
  union { unsigned u; float f; } v; v.u = ((unsigned)h) << 16;
  return v.f;
}

// direct global->LDS DMA, 16B per lane. LDS dst = wave-uniform base + lane*16.
__device__ __forceinline__ void gld_lds16(const unsigned short* g, unsigned short* l) {
  __builtin_amdgcn_global_load_lds((const __attribute__((address_space(1))) void*)g,
                                   (__attribute__((address_space(3))) void*)l, 16, 0, 0);
}

// ---------------- GroupNorm sums: 1024 blocks, one per (b,g,row); atomic partials ----------------
__global__ void gn_sums(const float* __restrict__ x, float* __restrict__ stats) {
  int bid = blockIdx.x;
  int bg = bid >> 4, row = bid & 15;
  int b = bg >> 5, g = bg & 31;
  const float* base = x + ((size_t)(b * C_ + g * 16 + row)) * HW_;
  float s = 0.f, s2 = 0.f;
  int t = threadIdx.x;
  #pragma unroll
  for (int i = 0; i < 4; ++i) {
    float4 v = *reinterpret_cast<const float4*>(base + (size_t)(t + i * 256) * 4);
    s  += v.x + v.y + v.z + v.w;
    s2 += v.x * v.x + v.y * v.y + v.z * v.z + v.w * v.w;
  }
  for (int off = 32; off; off >>= 1) { s += __shfl_down(s, off); s2 += __shfl_down(s2, off); }
  __shared__ float rs[4], rs2[4];
  int w = t >> 6;
  if ((t & 63) == 0) { rs[w] = s; rs2[w] = s2; }
  __syncthreads();
  if (t == 0) {
    atomicAdd(&stats[bg], rs[0] + rs[1] + rs[2] + rs[3]);
    atomicAdd(&stats[64 + bg], rs2[0] + rs2[1] + rs2[2] + rs2[3]);
  }
}

// ------------- normalize + transpose: x(b,c,n) f32 -> t(b,n,c) bf16 -------------
__global__ void build_t(const float* __restrict__ x, const float* __restrict__ stats,
                        const float* __restrict__ gamma, const float* __restrict__ beta,
                        unsigned short* __restrict__ tb) {
  __shared__ float lds[64 * 69];
  int n0 = blockIdx.x * 64, c0 = blockIdx.y * 64, b = blockIdx.z;
  int t = threadIdx.x;
  {
    int cl = t >> 2, ch = t & 3;
    int c = c0 + cl;
    int bg = b * 32 + (c >> 4);
    float s = stats[bg], s2v = stats[64 + bg];
    float mean = s * (1.f / 65536.f);
    float var = s2v * (1.f / 65536.f) - mean * mean;
    float rstd = rsqrtf(var + EPS_);
    float ga = gamma[c] * rstd;
    float be = beta[c] - mean * ga;
    const float* xr = x + ((size_t)(b * C_ + c)) * HW_ + n0 + ch * 16;
    #pragma unroll
    for (int i = 0; i < 4; ++i) {
      float4 v = *reinterpret_cast<const float4*>(xr + i * 4);
      int nl = ch * 16 + i * 4;
      lds[cl * 69 + nl + 0] = v.x * ga + be;
      lds[cl * 69 + nl + 1] = v.y * ga + be;
      lds[cl * 69 + nl + 2] = v.z * ga + be;
      lds[cl * 69 + nl + 3] = v.w * ga + be;
    }
  }
  __syncthreads();
  {
    int nl = t >> 2, cw = t & 3;
    unsigned short* orow = tb + ((size_t)(b * HW_ + n0 + nl)) * C_ + c0 + cw * 16;
    #pragma unroll
    for (int i = 0; i < 4; ++i) {
      ushort4 o4;
      o4.x = f2bf(lds[(cw * 16 + i * 4 + 0) * 69 + nl]);
      o4.y = f2bf(lds[(cw * 16 + i * 4 + 1) * 69 + nl]);
      o4.z = f2bf(lds[(cw * 16 + i * 4 + 2) * 69 + nl]);
      o4.w = f2bf(lds[(cw * 16 + i * 4 + 3) * 69 + nl]);
      *reinterpret_cast<ushort4*>(orow + i * 4) = o4;
    }
  }
}

// ---------------- f32 -> bf16 weight cast, all 4 weights in one launch ----------------
__global__ void cast_w4(const float* __restrict__ s0, const float* __restrict__ s1,
                        const float* __restrict__ s2, const float* __restrict__ s3,
                        unsigned short* __restrict__ dst) {
  int which = blockIdx.y;
  const float* src = which == 0 ? s0 : which == 1 ? s1 : which == 2 ? s2 : s3;
  int i = (blockIdx.x * 256 + threadIdx.x) * 4;
  float4 v = *reinterpret_cast<const float4*>(src + i);
  ushort4 o; o.x = f2bf(v.x); o.y = f2bf(v.y); o.z = f2bf(v.z); o.w = f2bf(v.w);
  *reinterpret_cast<ushort4*>(dst + (size_t)which * 262144 + i) = o;
}

// ---------------- fused Q/K/V^T projections, one launch ----------------
// z = which*2 + b; which 0: q = t.wq^T (bias/col), 1: k (bias/col), 2: vT = wv.t^T (bias/row)
__global__ __launch_bounds__(256, 2) void gemm_qkv(
    const unsigned short* __restrict__ tb, const unsigned short* __restrict__ wqkv,
    const float* __restrict__ bq, const float* __restrict__ bk, const float* __restrict__ bv,
    unsigned short* __restrict__ qb, unsigned short* __restrict__ kb,
    unsigned short* __restrict__ vTb) {
  __shared__ unsigned short Al[2][128 * 64];
  __shared__ unsigned short Bl[2][128 * 64];
  int z = blockIdx.z;
  int which = z >> 1, b = z & 1;
  const unsigned short* Ab = (which < 2) ? (tb + (size_t)b * HW_ * K_) : (wqkv + 2 * 262144);
  const unsigned short* Bb = (which < 2) ? (wqkv + which * 262144) : (tb + (size_t)b * HW_ * K_);
  int m0 = (which < 2) ? blockIdx.y * 128 : blockIdx.x * 128;
  int n0 = (which < 2) ? blockIdx.x * 128 : blockIdx.y * 128;
  int N = (which < 2) ? 512 : HW_;
  unsigned short* Cb = (which == 0) ? (qb + (size_t)b * HW_ * K_)
                     : (which == 1) ? (kb + (size_t)b * HW_ * K_)
                                    : (vTb + (size_t)b * C_ * HW_);
  const float* bias = (which == 0) ? bq : (which == 1) ? bk : bv;
  int t = threadIdx.x, lane = t & 63, w = t >> 6;
  int l15 = lane & 15, quad = lane >> 4;
  int mw = (w & 1) * 64, nw = (w >> 1) * 64;
  int sr8 = lane >> 3, sb = lane & 7;
  f32x4 acc[4][4] = {};

  #define G_STAGE(KC) do {                                                          \
    int pb = (KC) & 1;                                                              \
    _Pragma("unroll")                                                               \
    for (int q = 0; q < 4; ++q) {                                                   \
      int row = w * 32 + q * 8 + sr8;                                               \
      int gb = sb ^ (row & 7);                                                      \
      gld_lds16(Ab + (size_t)(m0 + row) * K_ + (KC) * 64 + gb * 8, &Al[pb][(w * 32 + q * 8) * 64]); \
      gld_lds16(Bb + (size_t)(n0 + row) * K_ + (KC) * 64 + gb * 8, &Bl[pb][(w * 32 + q * 8) * 64]); \
    }                                                                               \
  } while (0)

  G_STAGE(0);
  __syncthreads();
  for (int kc = 0; kc < 8; ++kc) {
    if (kc < 7) G_STAGE(kc + 1);
    const unsigned short* Ac = Al[kc & 1];
    const unsigned short* Bc = Bl[kc & 1];
    #pragma unroll
    for (int kk = 0; kk < 2; ++kk) {
      bf16x8 af[4];
      #pragma unroll
      for (int mt = 0; mt < 4; ++mt)
        af[mt] = *reinterpret_cast<const bf16x8*>(
            &Ac[(mw + mt * 16 + l15) * 64 + (((kk * 4 + quad) ^ (l15 & 7)) << 3)]);
      #pragma unroll
      for (int nt = 0; nt < 4; ++nt) {
        bf16x8 bfr = *reinterpret_cast<const bf16x8*>(
            &Bc[(nw + nt * 16 + l15) * 64 + (((kk * 4 + quad) ^ (l15 & 7)) << 3)]);
        #pragma unroll
        for (int mt = 0; mt < 4; ++mt)
          acc[mt][nt] = __builtin_amdgcn_mfma_f32_16x16x32_bf16(af[mt], bfr, acc[mt][nt], 0, 0, 0);
      }
    }
    __syncthreads();
  }
  #undef G_STAGE
  #pragma unroll
  for (int mt = 0; mt < 4; ++mt)
    #pragma unroll
    for (int nt = 0; nt < 4; ++nt)
      #pragma unroll
      for (int rr = 0; rr < 4; ++rr) {
        int row = m0 + mw + mt * 16 + quad * 4 + rr;
        int col = n0 + nw + nt * 16 + l15;
        float v = acc[mt][nt][rr] + ((which < 2) ? bias[col] : bias[row]);
        Cb[(size_t)row * N + col] = f2bf(v);
      }
}

// ---------------- final projection + residual (f32 out) ----------------
template <int MODE>
__global__ __launch_bounds__(256, 2) void gemm_bt(
    const unsigned short* __restrict__ A, long sA,
    const unsigned short* __restrict__ B, long sB,
    void* __restrict__ Cv, long sC, int M, int N,
    const float* __restrict__ bias,
    const float* __restrict__ resid, long sR) {
  __shared__ unsigned short Al[2][128 * 64];
  __shared__ unsigned short Bl[2][128 * 64];
  int z = blockIdx.z;
  const unsigned short* Ab = A + (size_t)z * sA;
  const unsigned short* Bb = B + (size_t)z * sB;
  int n0 = blockIdx.x * 128, m0 = blockIdx.y * 128;
  int t = threadIdx.x, lane = t & 63, w = t >> 6;
  int l15 = lane & 15, quad = lane >> 4;
  int mw = (w & 1) * 64, nw = (w >> 1) * 64;
  int sr8 = lane >> 3, sb = lane & 7;
  f32x4 acc[4][4] = {};

  #define G_STAGE(KC) do {                                                          \
    int pb = (KC) & 1;                                                              \
    _Pragma("unroll")                                                               \
    for (int q = 0; q < 4; ++q) {                                                   \
      int row = w * 32 + q * 8 + sr8;                                               \
      int gb = sb ^ (row & 7);                                                      \
      gld_lds16(Ab + (size_t)(m0 + row) * K_ + (KC) * 64 + gb * 8, &Al[pb][(w * 32 + q * 8) * 64]); \
      gld_lds16(Bb + (size_t)(n0 + row) * K_ + (KC) * 64 + gb * 8, &Bl[pb][(w * 32 + q * 8) * 64]); \
    }                                                                               \
  } while (0)

  G_STAGE(0);
  __syncthreads();
  for (int kc = 0; kc < 8; ++kc) {
    if (kc < 7) G_STAGE(kc + 1);
    const unsigned short* Ac = Al[kc & 1];
    const unsigned short* Bc = Bl[kc & 1];
    #pragma unroll
    for (int kk = 0; kk < 2; ++kk) {
      bf16x8 af[4];
      #pragma unroll
      for (int mt = 0; mt < 4; ++mt)
        af[mt] = *reinterpret_cast<const bf16x8*>(
            &Ac[(mw + mt * 16 + l15) * 64 + (((kk * 4 + quad) ^ (l15 & 7)) << 3)]);
      #pragma unroll
      for (int nt = 0; nt < 4; ++nt) {
        bf16x8 bfr = *reinterpret_cast<const bf16x8*>(
            &Bc[(nw + nt * 16 + l15) * 64 + (((kk * 4 + quad) ^ (l15 & 7)) << 3)]);
        #pragma unroll
        for (int mt = 0; mt < 4; ++mt)
          acc[mt][nt] = __builtin_amdgcn_mfma_f32_16x16x32_bf16(af[mt], bfr, acc[mt][nt], 0, 0, 0);
      }
    }
    __syncthreads();
  }
  #undef G_STAGE
  #pragma unroll
  for (int mt = 0; mt < 4; ++mt)
    #pragma unroll
    for (int nt = 0; nt < 4; ++nt)
      #pragma unroll
      for (int rr = 0; rr < 4; ++rr) {
        int row = m0 + mw + mt * 16 + quad * 4 + rr;
        int col = n0 + nw + nt * 16 + l15;
        float v = acc[mt][nt][rr];
        if (MODE == 0) {
          v += bias[col];
          reinterpret_cast<unsigned short*>(Cv)[(size_t)z * sC + (size_t)row * N + col] = f2bf(v);
        } else if (MODE == 1) {
          v += bias[row];
          reinterpret_cast<unsigned short*>(Cv)[(size_t)z * sC + (size_t)row * N + col] = f2bf(v);
        } else {
          v += bias[row];
          v += resid[(size_t)z * sR + (size_t)row * N + col];
          reinterpret_cast<float*>(Cv)[(size_t)z * sC + (size_t)row * N + col] = v;
        }
      }
}

// ------- flash attention (r7-verified form): Br=64, Bc=256; async DMA + XOR swizzle -------
// 2 rotating buffers, depth-1 prefetch, __syncthreads barriers. PV dc-inner with pa_r
// register reuse. 1 block/CU (register-pinned). Measured 142.5 us / MfmaUtil 19.5%.
__global__ __launch_bounds__(512, 2) void attn(
    const unsigned short* __restrict__ qg, const unsigned short* __restrict__ kg,
    const unsigned short* __restrict__ vg,  // vT: (b, c, n)
    unsigned short* __restrict__ opart, float* __restrict__ mpart, float* __restrict__ lpart) {
  __shared__ unsigned short KVb[2 * 16384];   // 2 x 32KB chunk buffers (128 rows x 128 cols)
  __shared__ unsigned short Pl[64 * 264];     // 33792 B
  __shared__ float sm_m[64], sm_l[64], sm_alpha[64], sm_red[128];
  int qt = blockIdx.x, jh = blockIdx.y, b = blockIdx.z;
  int t = threadIdx.x, lane = t & 63, w = t >> 6;
  int l15 = lane & 15, quad = lane >> 4;
  int l31 = lane & 31, hl = lane >> 5;
  int rw = w & 3, cw = w >> 2;      // S phase: 4 row-groups(16) x 2 col-halves
  int rw2 = w & 1, dg = w >> 1;     // PV phase: 2 row-groups(32) x 4 d-slots
  int m0 = qt * 64;
  if (t < 64) { sm_m[t] = NEG_INF_; sm_l[t] = 0.f; }

  // staging geometry: thread stages 4 x 16B; wave w covers 1KB blocks w*4+q (4 rows each)
  int st_r[4], st_kb[4];
  #pragma unroll
  for (int q = 0; q < 4; ++q) {
    int blk = w * 4 + q;
    st_r[q] = blk * 4 + (lane >> 4);          // row 0..127 within chunk
    st_kb[q] = (lane & 15) ^ (st_r[q] & 7);   // logical 16B block (col/8)
  }

  #define STAGE_K(JC, KC, J0) do {                                                  \
    const unsigned short* gb = kg + ((size_t)(b * HW_ + (J0) + (JC) * 128)) * K_ + (KC) * 128; \
    unsigned short* lb = KVb + ((((JC) * 4 + (KC)) & 1) << 14);                     \
    _Pragma("unroll")                                                               \
    for (int q = 0; q < 4; ++q)                                                     \
      gld_lds16(gb + (size_t)st_r[q] * K_ + st_kb[q] * 8, lb + (w * 4 + q) * 512);  \
  } while (0)

  // chunk index in PV = jc*4 + dc -> buffer parity = dc&1
  #define STAGE_V(DC, JC, J0) do {                                                 \
    const unsigned short* gb = vg + ((size_t)(b * K_ + (DC) * 128)) * HW_ + (J0) + (JC) * 128; \
    unsigned short* lb = KVb + (((DC) & 1) << 14);                                  \
    _Pragma("unroll")                                                               \
    for (int q = 0; q < 4; ++q)                                                     \
      gld_lds16(gb + (size_t)st_r[q] * HW_ + st_kb[q] * 8, lb + (w * 4 + q) * 512); \
  } while (0)

  bf16x8 qa[16];
  {
    const unsigned short* qrow = qg + ((size_t)(b * HW_ + m0 + rw * 16 + l15)) * K_ + quad * 8;
    #pragma unroll
    for (int kk = 0; kk < 16; ++kk)
      qa[kk] = *reinterpret_cast<const bf16x8*>(qrow + kk * 32);
  }
  f32x16 acc_o[4] = {};    // [dc]: d = dc*128 + dg*32 + l31

  int j0 = jh * 2048;
  STAGE_K(0, 0, j0);       // chunk 0 in flight
  __syncthreads();         // drains chunk 0; publishes sm init

  for (int it = 0; it < 8; ++it, j0 += 256) {
    f32x4 acc_s[8] = {};
    // ===== S phases: 8 chunks (jc 0..1) x (kc 0..3) =====
    #pragma unroll
    for (int c = 0; c < 8; ++c) {
      int jc = c >> 2, kc = c & 3;
      if (c < 7) { STAGE_K((c + 1) >> 2, (c + 1) & 3, j0); }
      else       { STAGE_V(0, 0, j0); }   // PV chunk 0 (parity 0)
      const unsigned short* bufc = KVb + ((c & 1) << 14);
      #pragma unroll
      for (int kk = 0; kk < 4; ++kk)
        #pragma unroll
        for (int ct = 0; ct < 4; ++ct) {
          int jr = cw * 64 + ct * 16 + l15;
          bf16x8 bfr = *reinterpret_cast<const bf16x8*>(
              &bufc[jr * 128 + (((kk * 4 + quad) ^ (l15 & 7)) << 3)]);
          acc_s[jc * 4 + ct] = __builtin_amdgcn_mfma_f32_16x16x32_bf16(qa[kc * 4 + kk], bfr, acc_s[jc * 4 + ct], 0, 0, 0);
        }
      __syncthreads();
    }
    // ===== softmax =====
    float mx[4];
    #pragma unroll
    for (int rr = 0; rr < 4; ++rr) {
      float m = NEG_INF_;
      #pragma unroll
      for (int s = 0; s < 8; ++s) {
        acc_s[s][rr] *= SCALE_;
        m = fmaxf(m, acc_s[s][rr]);
      }
      mx[rr] = m;
    }
    #pragma unroll
    for (int off = 1; off < 16; off <<= 1)
      #pragma unroll
      for (int rr = 0; rr < 4; ++rr)
        mx[rr] = fmaxf(mx[rr], __shfl_xor(mx[rr], off));
    if (l15 == 0)
      #pragma unroll
      for (int rr = 0; rr < 4; ++rr)
        sm_red[cw * 64 + rw * 16 + quad * 4 + rr] = mx[rr];
    __syncthreads();
    if (t < 64) {
      float mnew = fmaxf(sm_m[t], fmaxf(sm_red[t], sm_red[64 + t]));
      sm_alpha[t] = __expf(sm_m[t] - mnew);
      sm_m[t] = mnew;
    }
    __syncthreads();
    float sum[4] = {0.f, 0.f, 0.f, 0.f};
    #pragma unroll
    for (int s = 0; s < 8; ++s)
      #pragma unroll
      for (int rr = 0; rr < 4; ++rr) {
        int rowl = rw * 16 + quad * 4 + rr;
        float p = __expf(acc_s[s][rr] - sm_m[rowl]);
        sum[rr] += p;
        Pl[rowl * 264 + (s >> 2) * 128 + cw * 64 + (s & 3) * 16 + l15] = f2bf(p);
      }
    #pragma unroll
    for (int off = 1; off < 16; off <<= 1)
      #pragma unroll
      for (int rr = 0; rr < 4; ++rr)
        sum[rr] += __shfl_xor(sum[rr], off);
    if (l15 == 0)
      #pragma unroll
      for (int rr = 0; rr < 4; ++rr)
        sm_red[cw * 64 + rw * 16 + quad * 4 + rr] = sum[rr];
    __syncthreads();
    if (t < 64)
      sm_l[t] = sm_l[t] * sm_alpha[t] + sm_red[t] + sm_red[64 + t];
    // rescale O by alpha (32x32 C/D row mapping)
    #pragma unroll
    for (int r16 = 0; r16 < 16; ++r16) {
      int row = rw2 * 32 + (r16 & 3) + 8 * (r16 >> 2) + 4 * hl;
      float a = sm_alpha[row];
      #pragma unroll
      for (int dc = 0; dc < 4; ++dc)
        acc_o[dc][r16] *= a;
    }
    // ===== PV phases: 8 chunks, dc-inner (c: jc=c>>2, dc=c&3); pa_r reused across dc =====
    bf16x8 pa_r[8];
    #pragma unroll
    for (int c = 0; c < 8; ++c) {
      int jc = c >> 2, dc = c & 3;
      if ((c & 3) == 0) {
        #pragma unroll
        for (int ksx = 0; ksx < 8; ++ksx)
          pa_r[ksx] = *reinterpret_cast<const bf16x8*>(
              &Pl[(rw2 * 32 + l31) * 264 + jc * 128 + ksx * 16 + hl * 8]);
      }
      if (c < 7)          { STAGE_V((c + 1) & 3, (c + 1) >> 2, j0); }
      else if (it < 7)    { STAGE_K(0, 0, j0 + 256); }
      const unsigned short* bufc = KVb + ((c & 1) << 14);
      #pragma unroll
      for (int ksx = 0; ksx < 8; ++ksx) {
        bf16x8 vb = *reinterpret_cast<const bf16x8*>(
            &bufc[(dg * 32 + l31) * 128 + (((ksx * 2 + hl) ^ (l31 & 7)) << 3)]);
        acc_o[dc] = __builtin_amdgcn_mfma_f32_32x32x16_bf16(pa_r[ksx], vb, acc_o[dc], 0, 0, 0);
      }
      __syncthreads();
    }
  }
  #undef STAGE_K
  #undef STAGE_V
  // write partials (unnormalized O in bf16, running m and l)
  int part = jh * 2 + b;
  unsigned short* ob = opart + ((size_t)part * HW_ + m0) * 512;
  #pragma unroll
  for (int dc = 0; dc < 4; ++dc) {
    int d = dc * 128 + dg * 32 + l31;
    #pragma unroll
    for (int r16 = 0; r16 < 16; ++r16) {
      int row = rw2 * 32 + (r16 & 3) + 8 * (r16 >> 2) + 4 * hl;
      ob[(size_t)row * 512 + d] = f2bf(acc_o[dc][r16]);
    }
  }
  if (t < 64) {
    mpart[(size_t)part * HW_ + m0 + t] = sm_m[t];
    lpart[(size_t)part * HW_ + m0 + t] = sm_l[t];
  }
}

// ---------------- merge the two j-split halves ----------------
__global__ void merge_o(const unsigned short* __restrict__ opart, const float* __restrict__ mpart,
                        const float* __restrict__ lpart, unsigned short* __restrict__ om) {
  int rg = blockIdx.x;            // b*4096 + n
  int b = rg >> 12, n = rg & 4095;
  float m[2], l[2], M = NEG_INF_;
  #pragma unroll
  for (int p = 0; p < 2; ++p) {
    size_t r = (size_t)(p * 2 + b) * HW_ + n;
    m[p] = mpart[r]; l[p] = lpart[r];
    M = fmaxf(M, m[p]);
  }
  float wgt[2], L = 0.f;
  #pragma unroll
  for (int p = 0; p < 2; ++p) { wgt[p] = __expf(m[p] - M); L += l[p] * wgt[p]; }
  float inv = 1.f / L;
  unsigned short* orow = om + (size_t)rg * 512;
  for (int d = threadIdx.x; d < 512; d += 256) {
    float acc = 0.f;
    #pragma unroll
    for (int p = 0; p < 2; ++p)
      acc += bf2f(opart[((size_t)(p * 2 + b) * HW_ + n) * 512 + d]) * wgt[p];
    orow[d] = f2bf(acc * inv);
  }
}

extern "C" void kernel_launch(void* const* d_in, const int* in_sizes, int n_in,
                              void* d_out, int out_size, void* d_ws, size_t ws_size,
                              hipStream_t stream) {
  const float* x     = (const float*)d_in[0];
  const float* gamma = (const float*)d_in[1];
  const float* beta  = (const float*)d_in[2];
  const float* wq    = (const float*)d_in[3];
  const float* bq    = (const float*)d_in[4];
  const float* wk    = (const float*)d_in[5];
  const float* bk    = (const float*)d_in[6];
  const float* wv    = (const float*)d_in[7];
  const float* bv    = (const float*)d_in[8];
  const float* wp    = (const float*)d_in[9];
  const float* bp    = (const float*)d_in[10];
  float* out = (float*)d_out;

  char* ws = (char*)d_ws;
  size_t o = 0;
  float* stats          = (float*)(ws + o);          o += 1024;
  unsigned short* tb    = (unsigned short*)(ws + o); o += 8388608;   // om aliases tb after attn
  unsigned short* qb    = (unsigned short*)(ws + o); o += 8388608;
  unsigned short* kb    = (unsigned short*)(ws + o); o += 8388608;
  unsigned short* vTb   = (unsigned short*)(ws + o); o += 8388608;
  unsigned short* wqb   = (unsigned short*)(ws + o); o += 524288;
  unsigned short* wkb   = (unsigned short*)(ws + o); o += 524288;
  unsigned short* wvb   = (unsigned short*)(ws + o); o += 524288;
  unsigned short* wpb   = (unsigned short*)(ws + o); o += 524288;
  unsigned short* opart = (unsigned short*)(ws + o); o += 16777216;  // 4 parts bf16
  float* mpart          = (float*)(ws + o);          o += 65536;
  float* lpart          = (float*)(ws + o);          o += 65536;
  unsigned short* om    = tb;                                        // alias

  hipMemsetAsync(stats, 0, 512, stream);
  gn_sums<<<1024, 256, 0, stream>>>(x, stats);
  build_t<<<dim3(64, 8, 2), 256, 0, stream>>>(x, stats, gamma, beta, tb);
  cast_w4<<<dim3(256, 4), 256, 0, stream>>>(wq, wk, wv, wp, wqb);
  // fused q,k,vT projections
  gemm_qkv<<<dim3(4, 32, 6), 256, 0, stream>>>(tb, wqb, bq, bk, bv, qb, kb, vTb);
  attn<<<dim3(64, 2, 2), 512, 0, stream>>>(qb, kb, vTb, opart, mpart, lpart);
  merge_o<<<8192, 256, 0, stream>>>(opart, mpart, lpart, om);
  // out[c][n] = x + wp[c][:] . o[n][:] + bp[c]
  gemm_bt<2><<<dim3(32, 4, 2), 256, 0, stream>>>(wpb, 0, om, (long)HW_ * K_, out, (long)C_ * HW_, C_, HW_, bp, x, (long)C_ * HW_);
}